// Round 7
// baseline (505.888 us; speedup 1.0000x reference)
//
#include <hip/hip_runtime.h>

static constexpr int kN   = 50000;
static constexpr int kDin = 256;
static constexpr int kC   = 8;
static constexpr int kE   = 1600000;
static constexpr int kSteps = 5;

static constexpr int kNB      = 256;   // coarse buckets
static constexpr int kBucketW = 196;   // nodes per bucket (196*256 >= 50000)
static constexpr int kChunk   = 4096;  // edges per bin block
static constexpr int kEperB   = kE / kNB;  // 6250 edges per e-bucket (exact)

// ---------------- ws layout (bytes) ----------------
static constexpr size_t OFF_LOGB0 = 0;           // kN*8*4   = 1,600,000
static constexpr size_t OFF_BHIST = 1600000;     // 256*4
static constexpr size_t OFF_GBASE = 1601024;     // 257*4 -> pad
static constexpr size_t OFF_GCUR  = 1602112;     // 257*4 -> pad
static constexpr size_t OFF_START = 1603200;     // (kN+1)*4
static constexpr size_t OFF_REC   = 1803264;     // kE*4
static constexpr size_t OFF_INV   = 8203264;     // kE*4
static constexpr size_t OFF_MSGA  = 14603264;    // kE*8*2
static constexpr size_t OFF_MSGB  = 40203264;    // kE*8*2
static constexpr size_t OFF_SPOS  = 65803264;    // kE*4
static constexpr size_t OFF_SRCS  = 72203264;    // kE*4
static constexpr size_t OFF_RVS   = 78603264;    // kE*4
static constexpr size_t OFF_REC2  = 85003264;    // kE*8
static constexpr size_t OFF_GCUR2 = 97803264;    // 256*4
static constexpr size_t WS_NEEDED = 97804288;

// msg quantization: o = log((1-A)p + A) - K in [-3-K, -K], width exactly 3
static constexpr float kDEC   = 3.0f / 65535.0f;
static constexpr float kENC   = 65535.0f / 3.0f;
static constexpr float kOFF   = 3.2990003f;            // 3 + K
static constexpr float kA     = 0.049787068367863944f; // e^-3
static constexpr float kOneMA = 0.950212931632136f;    // 1 - A

// ---------------------------------------------------------------------------
// Fused init: blocks [0,1024) phase1 (log_b0 = log_softmax(xW+b)),
//             blocks [1024,1280) coarse dst-bucket histogram.
// ---------------------------------------------------------------------------
__global__ void __launch_bounds__(256) init_kernel(
    const float* __restrict__ x, const float* __restrict__ W,
    const float* __restrict__ bias,
    float* __restrict__ log_b0, float* __restrict__ log_b,
    const int* __restrict__ dst, int* __restrict__ bhist)
{
    __shared__ int h[kNB];
    if (blockIdx.x >= 1024) {
        h[threadIdx.x] = 0;
        __syncthreads();
        const int nthr = 256 * 256;
        for (int e = (blockIdx.x - 1024) * 256 + threadIdx.x; e < kE; e += nthr)
            atomicAdd(&h[dst[e] / kBucketW], 1);
        __syncthreads();
        if (h[threadIdx.x]) atomicAdd(&bhist[threadIdx.x], h[threadIdx.x]);
        return;
    }

    const int lane   = threadIdx.x & 63;
    const int wave   = (blockIdx.x * 256 + threadIdx.x) >> 6;
    const int nwaves = (1024 * 256) >> 6;

    float w[4][8];
#pragma unroll
    for (int j = 0; j < 4; ++j) {
        const float4* wp = reinterpret_cast<const float4*>(W + (size_t)(lane + 64 * j) * kC);
        float4 a = wp[0], b2 = wp[1];
        w[j][0] = a.x;  w[j][1] = a.y;  w[j][2] = a.z;  w[j][3] = a.w;
        w[j][4] = b2.x; w[j][5] = b2.y; w[j][6] = b2.z; w[j][7] = b2.w;
    }

    for (int row = wave; row < kN; row += nwaves) {
        const float* xr = x + (size_t)row * kDin;
        float acc[8] = {0.f, 0.f, 0.f, 0.f, 0.f, 0.f, 0.f, 0.f};
#pragma unroll
        for (int j = 0; j < 4; ++j) {
            float xv = xr[lane + 64 * j];
#pragma unroll
            for (int c = 0; c < 8; ++c) acc[c] = fmaf(xv, w[j][c], acc[c]);
        }
#pragma unroll
        for (int off = 32; off > 0; off >>= 1) {
#pragma unroll
            for (int c = 0; c < 8; ++c) acc[c] += __shfl_down(acc[c], off, 64);
        }
        if (lane == 0) {
            float z[8], m = -1e30f;
#pragma unroll
            for (int c = 0; c < 8; ++c) { z[c] = acc[c] + bias[c]; m = fmaxf(m, z[c]); }
            float s = 0.f;
#pragma unroll
            for (int c = 0; c < 8; ++c) s += __expf(z[c] - m);
            float lse = m + __logf(s);
#pragma unroll
            for (int c = 0; c < 8; ++c) {
                float v = z[c] - lse;
                log_b0[(size_t)row * 8 + c] = v;
                log_b[(size_t)row * 8 + c]  = v;
            }
        }
    }
}

// ---------------------------------------------------------------------------
// scan 256 dst-bucket counts -> gbase/gcur; also init gcur2 (uniform buckets)
// ---------------------------------------------------------------------------
__global__ void __launch_bounds__(256) bucket_scan_kernel(
    const int* __restrict__ bhist, int* __restrict__ gbase, int* __restrict__ gcur,
    int* __restrict__ gcur2)
{
    __shared__ int sh[kNB];
    const int tid = threadIdx.x;
    int v = bhist[tid];
    sh[tid] = v;
    __syncthreads();
#pragma unroll
    for (int off = 1; off < kNB; off <<= 1) {
        int t = (tid >= off) ? sh[tid - off] : 0;
        __syncthreads();
        sh[tid] += t;
        __syncthreads();
    }
    int excl = sh[tid] - v;
    gbase[tid] = excl;
    gcur[tid]  = excl;
    gcur2[tid] = tid * kEperB;
    if (tid == kNB - 1) { gbase[kNB] = sh[tid]; gcur[kNB] = sh[tid]; }
}

// ---------------------------------------------------------------------------
// bin: 4096-edge chunks -> dst-bucket-contiguous runs of (local<<21|e) records
// ---------------------------------------------------------------------------
__global__ void __launch_bounds__(256) bin_kernel(
    const int* __restrict__ dst, int* __restrict__ gcur,
    unsigned int* __restrict__ recbuf)
{
    __shared__ int hist[kNB];
    __shared__ int sh[kNB];
    __shared__ int cursor[kNB];
    __shared__ int gdbase[kNB];
    __shared__ unsigned int buf[kChunk];

    const int tid = threadIdx.x;
    const int e0  = blockIdx.x * kChunk;
    const int n   = (kE - e0 < kChunk) ? (kE - e0) : kChunk;

    hist[tid] = 0;
    __syncthreads();

    int myb[16];
    unsigned int rec[16];
#pragma unroll
    for (int k = 0; k < 16; ++k) {
        const int i = tid + k * 256;
        myb[k] = -1;
        if (i < n) {
            const int d = dst[e0 + i];
            const int b = d / kBucketW;
            myb[k] = b;
            rec[k] = ((unsigned int)(d - b * kBucketW) << 21) | (unsigned int)(e0 + i);
            atomicAdd(&hist[b], 1);
        }
    }
    __syncthreads();

    const int cnt = hist[tid];
    sh[tid] = cnt;
    __syncthreads();
#pragma unroll
    for (int off = 1; off < kNB; off <<= 1) {
        int t = (tid >= off) ? sh[tid - off] : 0;
        __syncthreads();
        sh[tid] += t;
        __syncthreads();
    }
    const int excl = sh[tid] - cnt;
    cursor[tid] = excl;
    __syncthreads();

#pragma unroll
    for (int k = 0; k < 16; ++k) {
        if (myb[k] >= 0) {
            int slot = atomicAdd(&cursor[myb[k]], 1);
            buf[slot] = rec[k];
        }
    }
    gdbase[tid] = (cnt > 0) ? atomicAdd(&gcur[tid], cnt) : 0;
    __syncthreads();

    for (int i = tid; i < n; i += 256) {
        int b = 0;
#pragma unroll
        for (int step = 128; step >= 1; step >>= 1)
            if (b + step <= kNB - 1 && sh[b + step - 1] <= i) b += step;
        const int off_in_b = i - (sh[b] - hist[b]);
        recbuf[gdbase[b] + off_in_b] = buf[i];
    }
}

// ---------------------------------------------------------------------------
// fine: per dst-bucket counting sort -> start[] and inv[] (hot region)
// ---------------------------------------------------------------------------
__global__ void __launch_bounds__(256) fine_kernel(
    const int* __restrict__ gbase, const unsigned int* __restrict__ recbuf,
    int* __restrict__ start, int* __restrict__ inv)
{
    __shared__ int hist[kNB];
    __shared__ int sh[kNB];
    __shared__ int lcur[kNB];

    const int tid = threadIdx.x;
    const int b   = blockIdx.x;
    const int nb0 = b * kBucketW;
    const int nnode = (kN - nb0 < kBucketW) ? (kN - nb0) : kBucketW;
    const int rb = gbase[b], re = gbase[b + 1];

    hist[tid] = 0;
    __syncthreads();

    for (int i = rb + tid; i < re; i += 256)
        atomicAdd(&hist[recbuf[i] >> 21], 1);
    __syncthreads();

    const int cnt = hist[tid];
    sh[tid] = cnt;
    __syncthreads();
#pragma unroll
    for (int off = 1; off < kNB; off <<= 1) {
        int t = (tid >= off) ? sh[tid - off] : 0;
        __syncthreads();
        sh[tid] += t;
        __syncthreads();
    }
    const int excl = sh[tid] - cnt;
    lcur[tid] = rb + excl;
    if (tid < nnode) start[nb0 + tid] = rb + excl;
    if (b == gridDim.x - 1 && tid == 0) start[kN] = kE;
    __syncthreads();

    for (int i = rb + tid; i < re; i += 256) {
        const unsigned int r = recbuf[i];
        const int p = atomicAdd(&lcur[r >> 21], 1);
        inv[p] = (int)(r & 0x1FFFFFu);
    }
}

// ---------------------------------------------------------------------------
// bin2: route (p, e=inv[p]) records into e-bucket runs (u64 records).
// Each e-bucket has EXACTLY kEperB records (inv is a permutation).
// ---------------------------------------------------------------------------
__global__ void __launch_bounds__(256) bin2_kernel(
    const int* __restrict__ inv, int* __restrict__ gcur2,
    unsigned long long* __restrict__ recbuf2)
{
    __shared__ int hist[kNB];
    __shared__ int sh[kNB];
    __shared__ int cursor[kNB];
    __shared__ int gdbase[kNB];
    __shared__ unsigned long long buf[kChunk];

    const int tid = threadIdx.x;
    const int p0  = blockIdx.x * kChunk;
    const int n   = (kE - p0 < kChunk) ? (kE - p0) : kChunk;

    hist[tid] = 0;
    __syncthreads();

    int myb[16];
    unsigned long long rec[16];
#pragma unroll
    for (int k = 0; k < 16; ++k) {
        const int i = tid + k * 256;
        myb[k] = -1;
        if (i < n) {
            const int e = inv[p0 + i];
            const int b = e / kEperB;
            myb[k] = b;
            rec[k] = ((unsigned long long)(e - b * kEperB) << 32) | (unsigned int)(p0 + i);
            atomicAdd(&hist[b], 1);
        }
    }
    __syncthreads();

    const int cnt = hist[tid];
    sh[tid] = cnt;
    __syncthreads();
#pragma unroll
    for (int off = 1; off < kNB; off <<= 1) {
        int t = (tid >= off) ? sh[tid - off] : 0;
        __syncthreads();
        sh[tid] += t;
        __syncthreads();
    }
    const int excl = sh[tid] - cnt;
    cursor[tid] = excl;
    __syncthreads();

#pragma unroll
    for (int k = 0; k < 16; ++k) {
        if (myb[k] >= 0) {
            int slot = atomicAdd(&cursor[myb[k]], 1);
            buf[slot] = rec[k];
        }
    }
    gdbase[tid] = (cnt > 0) ? atomicAdd(&gcur2[tid], cnt) : 0;
    __syncthreads();

    for (int i = tid; i < n; i += 256) {
        int b = 0;
#pragma unroll
        for (int step = 128; step >= 1; step >>= 1)
            if (b + step <= kNB - 1 && sh[b + step - 1] <= i) b += step;
        const int off_in_b = i - (sh[b] - hist[b]);
        recbuf2[gdbase[b] + off_in_b] = buf[i];
    }
}

// ---------------------------------------------------------------------------
// fine2: per e-bucket, slot[e_local] = p (no conflicts; permutation),
//        then write spos contiguously. Zero atomics, zero scans.
// ---------------------------------------------------------------------------
__global__ void __launch_bounds__(256) fine2_kernel(
    const unsigned long long* __restrict__ recbuf2, int* __restrict__ spos)
{
    __shared__ int slot[kEperB];
    const int tid  = threadIdx.x;
    const int base = blockIdx.x * kEperB;

    for (int i = tid; i < kEperB; i += 256) {
        const unsigned long long r = recbuf2[base + i];
        slot[(int)(r >> 32)] = (int)(r & 0xFFFFFFFFu);
    }
    __syncthreads();
    for (int i = tid; i < kEperB; i += 256)
        spos[base + i] = slot[i];
}

// ---------------------------------------------------------------------------
// build: src_s[p] = src[inv[p]];  rv_s[p] = spos[rv[inv[p]]]
// ---------------------------------------------------------------------------
__global__ void __launch_bounds__(256) build_kernel(
    const int* __restrict__ inv, const int* __restrict__ src,
    const int* __restrict__ rv, const int* __restrict__ spos,
    int* __restrict__ src_s, int* __restrict__ rv_s)
{
    const int p0 = (blockIdx.x * 256 + threadIdx.x) * 2;
    if (p0 >= kE) return;
    const int2 ee = *reinterpret_cast<const int2*>(inv + p0);
    const int sx = src[ee.x], sy = src[ee.y];
    const int rx = rv[ee.x],  ry = rv[ee.y];
    const int qx = spos[rx],  qy = spos[ry];
    *reinterpret_cast<int2*>(src_s + p0) = make_int2(sx, sy);
    *reinterpret_cast<int2*>(rv_s + p0)  = make_int2(qx, qy);
}

// ---------------------------------------------------------------------------
// Edge kernel, DST-SORTED order, 2 edges/thread.
//   t = log_b[src_s[i]] - dec(mold[rv_s[i]]);  msg -> mnew[i] (contiguous)
// ---------------------------------------------------------------------------
template <bool FIRST>
__global__ void __launch_bounds__(256) edge_kernel(
    const int* __restrict__ src_s, const int* __restrict__ rv_s,
    const float* __restrict__ log_b,
    const unsigned short* __restrict__ mold,
    unsigned short* __restrict__ mnew)
{
    const int i0 = (blockIdx.x * 256 + threadIdx.x) * 2;
    if (i0 >= kE) return;

    const int2 sp = *reinterpret_cast<const int2*>(src_s + i0);

    const float4* lba = reinterpret_cast<const float4*>(log_b + (size_t)sp.x * 8);
    const float4* lbb = reinterpret_cast<const float4*>(log_b + (size_t)sp.y * 8);
    float4 a0 = lba[0], a1 = lba[1];
    float4 b0 = lbb[0], b1 = lbb[1];

    uint4 ma, mb;
    if (!FIRST) {
        const int2 rp = *reinterpret_cast<const int2*>(rv_s + i0);
        ma = *reinterpret_cast<const uint4*>(mold + (size_t)rp.x * 8);
        mb = *reinterpret_cast<const uint4*>(mold + (size_t)rp.y * 8);
    }

    float ta[8] = {a0.x, a0.y, a0.z, a0.w, a1.x, a1.y, a1.z, a1.w};
    float tb[8] = {b0.x, b0.y, b0.z, b0.w, b1.x, b1.y, b1.z, b1.w};
    if (!FIRST) {
        ta[0] -= (float)(ma.x & 0xffffu) * kDEC;  ta[1] -= (float)(ma.x >> 16) * kDEC;
        ta[2] -= (float)(ma.y & 0xffffu) * kDEC;  ta[3] -= (float)(ma.y >> 16) * kDEC;
        ta[4] -= (float)(ma.z & 0xffffu) * kDEC;  ta[5] -= (float)(ma.z >> 16) * kDEC;
        ta[6] -= (float)(ma.w & 0xffffu) * kDEC;  ta[7] -= (float)(ma.w >> 16) * kDEC;
        tb[0] -= (float)(mb.x & 0xffffu) * kDEC;  tb[1] -= (float)(mb.x >> 16) * kDEC;
        tb[2] -= (float)(mb.y & 0xffffu) * kDEC;  tb[3] -= (float)(mb.y >> 16) * kDEC;
        tb[4] -= (float)(mb.z & 0xffffu) * kDEC;  tb[5] -= (float)(mb.z >> 16) * kDEC;
        tb[6] -= (float)(mb.w & 0xffffu) * kDEC;  tb[7] -= (float)(mb.w >> 16) * kDEC;
    }

    unsigned int qa[8], qb[8];
    {
        float mx = ta[0];
#pragma unroll
        for (int c = 1; c < 8; ++c) mx = fmaxf(mx, ta[c]);
        float p[8], S = 0.f;
#pragma unroll
        for (int c = 0; c < 8; ++c) { p[c] = __expf(ta[c] - mx); S += p[c]; }
        const float coef = kOneMA / S;
#pragma unroll
        for (int c = 0; c < 8; ++c) {
            float u  = fmaf(coef, p[c], kA);
            float qq = fmaf(__logf(u), kENC, 65535.0f);
            qq = fminf(fmaxf(qq + 0.5f, 0.0f), 65535.0f);
            qa[c] = (unsigned int)qq;
        }
    }
    {
        float mx = tb[0];
#pragma unroll
        for (int c = 1; c < 8; ++c) mx = fmaxf(mx, tb[c]);
        float p[8], S = 0.f;
#pragma unroll
        for (int c = 0; c < 8; ++c) { p[c] = __expf(tb[c] - mx); S += p[c]; }
        const float coef = kOneMA / S;
#pragma unroll
        for (int c = 0; c < 8; ++c) {
            float u  = fmaf(coef, p[c], kA);
            float qq = fmaf(__logf(u), kENC, 65535.0f);
            qq = fminf(fmaxf(qq + 0.5f, 0.0f), 65535.0f);
            qb[c] = (unsigned int)qq;
        }
    }

    uint4* mn = reinterpret_cast<uint4*>(mnew + (size_t)i0 * 8);
    mn[0] = make_uint4(qa[0] | (qa[1] << 16), qa[2] | (qa[3] << 16),
                       qa[4] | (qa[5] << 16), qa[6] | (qa[7] << 16));
    mn[1] = make_uint4(qb[0] | (qb[1] << 16), qb[2] | (qb[3] << 16),
                       qb[4] | (qb[5] << 16), qb[6] | (qb[7] << 16));
}

// ---------------------------------------------------------------------------
// Node kernel: 2 nodes/wave, STREAMING contiguous msg runs (exact int sum).
// Normalize only on FINAL step (softmax shift-invariant).
// ---------------------------------------------------------------------------
template <bool FINAL>
__global__ void __launch_bounds__(256) node_kernel(
    const int* __restrict__ start,
    const unsigned short* __restrict__ msgq,
    const float* __restrict__ log_b0, float* __restrict__ log_b)
{
    const int wid  = (blockIdx.x * 256 + threadIdx.x) >> 6;
    const int lane = threadIdx.x & 63;
    const int half = lane >> 5;
    const int l32  = lane & 31;
    const int n = wid * 2 + half;
    if (n >= kN) return;

    const int s = start[n], e2 = start[n + 1];

    int q[8] = {0, 0, 0, 0, 0, 0, 0, 0};
    for (int j = s + l32; j < e2; j += 32) {
        const uint4 m = *reinterpret_cast<const uint4*>(msgq + (size_t)j * 8);
        q[0] += (int)(m.x & 0xffffu);  q[1] += (int)(m.x >> 16);
        q[2] += (int)(m.y & 0xffffu);  q[3] += (int)(m.y >> 16);
        q[4] += (int)(m.z & 0xffffu);  q[5] += (int)(m.z >> 16);
        q[6] += (int)(m.w & 0xffffu);  q[7] += (int)(m.w >> 16);
    }
#pragma unroll
    for (int off = 1; off <= 16; off <<= 1) {
#pragma unroll
        for (int c = 0; c < 8; ++c) q[c] += __shfl_xor(q[c], off, 64);
    }

    if (l32 == 0) {
        const int deg = e2 - s;
        const float base = -kOFF * (float)deg;
        const float4* lb0 = reinterpret_cast<const float4*>(log_b0 + (size_t)n * 8);
        float4 c0 = lb0[0], c1 = lb0[1];
        float v[8];
        v[0] = fmaf((float)q[0], kDEC, base) + c0.x;
        v[1] = fmaf((float)q[1], kDEC, base) + c0.y;
        v[2] = fmaf((float)q[2], kDEC, base) + c0.z;
        v[3] = fmaf((float)q[3], kDEC, base) + c0.w;
        v[4] = fmaf((float)q[4], kDEC, base) + c1.x;
        v[5] = fmaf((float)q[5], kDEC, base) + c1.y;
        v[6] = fmaf((float)q[6], kDEC, base) + c1.z;
        v[7] = fmaf((float)q[7], kDEC, base) + c1.w;
        if (FINAL) {
            float m = v[0];
#pragma unroll
            for (int c = 1; c < 8; ++c) m = fmaxf(m, v[c]);
            float sum = 0.f;
#pragma unroll
            for (int c = 0; c < 8; ++c) sum += __expf(v[c] - m);
            float lse = m + __logf(sum);
#pragma unroll
            for (int c = 0; c < 8; ++c) v[c] -= lse;
        }
        float4* lb = reinterpret_cast<float4*>(log_b + (size_t)n * 8);
        lb[0] = make_float4(v[0], v[1], v[2], v[3]);
        lb[1] = make_float4(v[4], v[5], v[6], v[7]);
    }
}

extern "C" void kernel_launch(void* const* d_in, const int* in_sizes, int n_in,
                              void* d_out, int out_size, void* d_ws, size_t ws_size,
                              hipStream_t stream) {
    const float* x    = (const float*)d_in[0];
    const float* W    = (const float*)d_in[1];
    const float* bias = (const float*)d_in[2];
    const int*   ei   = (const int*)d_in[3];
    const int*   rv   = (const int*)d_in[4];
    const int* src = ei;
    const int* dst = ei + kE;
    float* out = (float*)d_out;

    if (ws_size < WS_NEEDED) return;

    char* ws = (char*)d_ws;
    float* log_b0 = (float*)(ws + OFF_LOGB0);
    int*   bhist  = (int*)(ws + OFF_BHIST);
    int*   gbase  = (int*)(ws + OFF_GBASE);
    int*   gcur   = (int*)(ws + OFF_GCUR);
    int*   start  = (int*)(ws + OFF_START);
    unsigned int* recbuf = (unsigned int*)(ws + OFF_REC);
    int*   inv    = (int*)(ws + OFF_INV);
    unsigned short* msgA = (unsigned short*)(ws + OFF_MSGA);
    unsigned short* msgB = (unsigned short*)(ws + OFF_MSGB);
    int*   spos   = (int*)(ws + OFF_SPOS);
    int*   src_s  = (int*)(ws + OFF_SRCS);
    int*   rv_s   = (int*)(ws + OFF_RVS);
    unsigned long long* recbuf2 = (unsigned long long*)(ws + OFF_REC2);
    int*   gcur2  = (int*)(ws + OFF_GCUR2);

    const int edgeBlocks = (kE / 2 + 255) / 256;            // 3125
    const int nodeBlocks = ((kN + 1) / 2 * 64 + 255) / 256; // 6250
    const int binBlocks  = (kE + kChunk - 1) / kChunk;      // 391

    (void)hipMemsetAsync(bhist, 0, kNB * sizeof(int), stream);
    init_kernel<<<1280, 256, 0, stream>>>(x, W, bias, log_b0, out, dst, bhist);
    bucket_scan_kernel<<<1, 256, 0, stream>>>(bhist, gbase, gcur, gcur2);
    bin_kernel<<<binBlocks, 256, 0, stream>>>(dst, gcur, recbuf);
    fine_kernel<<<kNB, 256, 0, stream>>>(gbase, recbuf, start, inv);
    bin2_kernel<<<binBlocks, 256, 0, stream>>>(inv, gcur2, recbuf2);
    fine2_kernel<<<kNB, 256, 0, stream>>>(recbuf2, spos);
    build_kernel<<<edgeBlocks, 256, 0, stream>>>(inv, src, rv, spos, src_s, rv_s);

    // step 0 (uniform initial msg cancels in softmax)
    edge_kernel<true><<<edgeBlocks, 256, 0, stream>>>(src_s, rv_s, out, msgB, msgA);
    node_kernel<false><<<nodeBlocks, 256, 0, stream>>>(start, msgA, log_b0, out);

    unsigned short* cur = msgA;
    unsigned short* nxt = msgB;
    for (int it = 1; it < kSteps; ++it) {
        edge_kernel<false><<<edgeBlocks, 256, 0, stream>>>(src_s, rv_s, out, cur, nxt);
        if (it == kSteps - 1)
            node_kernel<true><<<nodeBlocks, 256, 0, stream>>>(start, nxt, log_b0, out);
        else
            node_kernel<false><<<nodeBlocks, 256, 0, stream>>>(start, nxt, log_b0, out);
        unsigned short* tmp = cur; cur = nxt; nxt = tmp;
    }
}

// Round 8
// 470.725 us; speedup vs baseline: 1.0747x; 1.0747x over previous
//
#include <hip/hip_runtime.h>

static constexpr int kN   = 50000;
static constexpr int kDin = 256;
static constexpr int kC   = 8;
static constexpr int kE   = 1600000;
static constexpr int kSteps = 5;

static constexpr int kNB      = 256;   // coarse buckets
static constexpr int kBucketW = 196;   // nodes per bucket (196*256 >= 50000)
static constexpr int kChunk   = 4096;  // edges per bin block
static constexpr int kEperB   = kE / kNB;  // 6250 edges per e-bucket (exact)

// ---------------- ws layout (bytes) ----------------
static constexpr size_t OFF_LOGB0 = 0;            // kN*8*4  = 1,600,000
static constexpr size_t OFF_BHIST = 1600000;      // 256*4
static constexpr size_t OFF_GBASE = 1601024;      // 257*4 -> pad
static constexpr size_t OFF_GCUR  = 1602112;      // 257*4 -> pad
static constexpr size_t OFF_START = 1603200;      // (kN+1)*4
static constexpr size_t OFF_REC   = 1803264;      // kE*4  = 6,400,000
static constexpr size_t OFF_PAY   = 8203264;      // kE*8  = 12,800,000
static constexpr size_t OFF_INV   = 21003264;     // kE*4
static constexpr size_t OFF_MSGA  = 27403264;     // kE*8*2
static constexpr size_t OFF_MSGB  = 53003264;     // kE*8*2
static constexpr size_t OFF_SPOS  = 78603264;     // kE*4
static constexpr size_t OFF_SRCS  = 85003264;     // kE*2 (u16)
static constexpr size_t OFF_RVT   = 88203264;     // kE*4
static constexpr size_t OFF_RVS   = 94603264;     // kE*4
static constexpr size_t OFF_REC2  = 101003264;    // kE*8
static constexpr size_t OFF_GCUR2 = 113803264;    // 256*4
static constexpr size_t WS_NEEDED = 113804288;

// msg quantization: o = log((1-A)p + A) - K in [-3-K, -K], width exactly 3
static constexpr float kDEC   = 3.0f / 65535.0f;
static constexpr float kENC   = 65535.0f / 3.0f;
static constexpr float kOFF   = 3.2990003f;            // 3 + K
static constexpr float kA     = 0.049787068367863944f; // e^-3
static constexpr float kOneMA = 0.950212931632136f;    // 1 - A

// ---------------------------------------------------------------------------
// Fused init: blocks [0,1024) phase1 (log_b0 = log_softmax(xW+b)),
//             blocks [1024,1280) coarse dst-bucket histogram.
// ---------------------------------------------------------------------------
__global__ void __launch_bounds__(256) init_kernel(
    const float* __restrict__ x, const float* __restrict__ W,
    const float* __restrict__ bias,
    float* __restrict__ log_b0, float* __restrict__ log_b,
    const int* __restrict__ dst, int* __restrict__ bhist)
{
    __shared__ int h[kNB];
    if (blockIdx.x >= 1024) {
        h[threadIdx.x] = 0;
        __syncthreads();
        const int nthr = 256 * 256;
        for (int e = (blockIdx.x - 1024) * 256 + threadIdx.x; e < kE; e += nthr)
            atomicAdd(&h[dst[e] / kBucketW], 1);
        __syncthreads();
        if (h[threadIdx.x]) atomicAdd(&bhist[threadIdx.x], h[threadIdx.x]);
        return;
    }

    const int lane   = threadIdx.x & 63;
    const int wave   = (blockIdx.x * 256 + threadIdx.x) >> 6;
    const int nwaves = (1024 * 256) >> 6;

    float w[4][8];
#pragma unroll
    for (int j = 0; j < 4; ++j) {
        const float4* wp = reinterpret_cast<const float4*>(W + (size_t)(lane + 64 * j) * kC);
        float4 a = wp[0], b2 = wp[1];
        w[j][0] = a.x;  w[j][1] = a.y;  w[j][2] = a.z;  w[j][3] = a.w;
        w[j][4] = b2.x; w[j][5] = b2.y; w[j][6] = b2.z; w[j][7] = b2.w;
    }

    for (int row = wave; row < kN; row += nwaves) {
        const float* xr = x + (size_t)row * kDin;
        float acc[8] = {0.f, 0.f, 0.f, 0.f, 0.f, 0.f, 0.f, 0.f};
#pragma unroll
        for (int j = 0; j < 4; ++j) {
            float xv = xr[lane + 64 * j];
#pragma unroll
            for (int c = 0; c < 8; ++c) acc[c] = fmaf(xv, w[j][c], acc[c]);
        }
#pragma unroll
        for (int off = 32; off > 0; off >>= 1) {
#pragma unroll
            for (int c = 0; c < 8; ++c) acc[c] += __shfl_down(acc[c], off, 64);
        }
        if (lane == 0) {
            float z[8], m = -1e30f;
#pragma unroll
            for (int c = 0; c < 8; ++c) { z[c] = acc[c] + bias[c]; m = fmaxf(m, z[c]); }
            float s = 0.f;
#pragma unroll
            for (int c = 0; c < 8; ++c) s += __expf(z[c] - m);
            float lse = m + __logf(s);
#pragma unroll
            for (int c = 0; c < 8; ++c) {
                float v = z[c] - lse;
                log_b0[(size_t)row * 8 + c] = v;
                log_b[(size_t)row * 8 + c]  = v;
            }
        }
    }
}

// ---------------------------------------------------------------------------
// scan 256 dst-bucket counts -> gbase/gcur; also init gcur2 (uniform buckets)
// ---------------------------------------------------------------------------
__global__ void __launch_bounds__(256) bucket_scan_kernel(
    const int* __restrict__ bhist, int* __restrict__ gbase, int* __restrict__ gcur,
    int* __restrict__ gcur2)
{
    __shared__ int sh[kNB];
    const int tid = threadIdx.x;
    int v = bhist[tid];
    sh[tid] = v;
    __syncthreads();
#pragma unroll
    for (int off = 1; off < kNB; off <<= 1) {
        int t = (tid >= off) ? sh[tid - off] : 0;
        __syncthreads();
        sh[tid] += t;
        __syncthreads();
    }
    int excl = sh[tid] - v;
    gbase[tid] = excl;
    gcur[tid]  = excl;
    gcur2[tid] = tid * kEperB;
    if (tid == kNB - 1) { gbase[kNB] = sh[tid]; gcur[kNB] = sh[tid]; }
}

// ---------------------------------------------------------------------------
// bin: 4096-edge chunks -> dst-bucket-contiguous runs.
//   key u32 = local(8b)<<21 | e(21b)
//   pay u64 = src(16b)<<21 | rv(21b)       (carried so no later gathers)
// ---------------------------------------------------------------------------
__global__ void __launch_bounds__(256) bin_kernel(
    const int* __restrict__ dst, const int* __restrict__ src,
    const int* __restrict__ rv, int* __restrict__ gcur,
    unsigned int* __restrict__ recbuf, unsigned long long* __restrict__ paybuf)
{
    __shared__ int hist[kNB];
    __shared__ int sh[kNB];
    __shared__ int cursor[kNB];
    __shared__ int gdbase[kNB];
    __shared__ unsigned int buf[kChunk];
    __shared__ unsigned long long pbuf[kChunk];

    const int tid = threadIdx.x;
    const int e0  = blockIdx.x * kChunk;
    const int n   = (kE - e0 < kChunk) ? (kE - e0) : kChunk;

    hist[tid] = 0;
    __syncthreads();

    int myb[16];
    unsigned int rec[16];
    unsigned long long pay[16];
#pragma unroll
    for (int k = 0; k < 16; ++k) {
        const int i = tid + k * 256;
        myb[k] = -1;
        if (i < n) {
            const int d = dst[e0 + i];
            const int b = d / kBucketW;
            myb[k] = b;
            rec[k] = ((unsigned int)(d - b * kBucketW) << 21) | (unsigned int)(e0 + i);
            pay[k] = ((unsigned long long)(unsigned int)src[e0 + i] << 21)
                   | (unsigned int)rv[e0 + i];
            atomicAdd(&hist[b], 1);
        }
    }
    __syncthreads();

    const int cnt = hist[tid];
    sh[tid] = cnt;
    __syncthreads();
#pragma unroll
    for (int off = 1; off < kNB; off <<= 1) {
        int t = (tid >= off) ? sh[tid - off] : 0;
        __syncthreads();
        sh[tid] += t;
        __syncthreads();
    }
    const int excl = sh[tid] - cnt;
    cursor[tid] = excl;
    __syncthreads();

#pragma unroll
    for (int k = 0; k < 16; ++k) {
        if (myb[k] >= 0) {
            int slot = atomicAdd(&cursor[myb[k]], 1);
            buf[slot]  = rec[k];
            pbuf[slot] = pay[k];
        }
    }
    gdbase[tid] = (cnt > 0) ? atomicAdd(&gcur[tid], cnt) : 0;
    __syncthreads();

    for (int i = tid; i < n; i += 256) {
        int b = 0;
#pragma unroll
        for (int step = 128; step >= 1; step >>= 1)
            if (b + step <= kNB - 1 && sh[b + step - 1] <= i) b += step;
        const int off_in_b = i - (sh[b] - hist[b]);
        recbuf[gdbase[b] + off_in_b] = buf[i];
        paybuf[gdbase[b] + off_in_b] = pbuf[i];
    }
}

// ---------------------------------------------------------------------------
// fine: per dst-bucket counting sort -> start[], inv[], src_s[] (u16), rvt[]
// All permuted writes land in this bucket's hot region.
// ---------------------------------------------------------------------------
__global__ void __launch_bounds__(256) fine_kernel(
    const int* __restrict__ gbase, const unsigned int* __restrict__ recbuf,
    const unsigned long long* __restrict__ paybuf,
    int* __restrict__ start, int* __restrict__ inv,
    unsigned short* __restrict__ src_s, int* __restrict__ rvt)
{
    __shared__ int hist[kNB];
    __shared__ int sh[kNB];
    __shared__ int lcur[kNB];

    const int tid = threadIdx.x;
    const int b   = blockIdx.x;
    const int nb0 = b * kBucketW;
    const int nnode = (kN - nb0 < kBucketW) ? (kN - nb0) : kBucketW;
    const int rb = gbase[b], re = gbase[b + 1];

    hist[tid] = 0;
    __syncthreads();

    for (int i = rb + tid; i < re; i += 256)
        atomicAdd(&hist[recbuf[i] >> 21], 1);
    __syncthreads();

    const int cnt = hist[tid];
    sh[tid] = cnt;
    __syncthreads();
#pragma unroll
    for (int off = 1; off < kNB; off <<= 1) {
        int t = (tid >= off) ? sh[tid - off] : 0;
        __syncthreads();
        sh[tid] += t;
        __syncthreads();
    }
    const int excl = sh[tid] - cnt;
    lcur[tid] = rb + excl;
    if (tid < nnode) start[nb0 + tid] = rb + excl;
    if (b == gridDim.x - 1 && tid == 0) start[kN] = kE;
    __syncthreads();

    for (int i = rb + tid; i < re; i += 256) {
        const unsigned int r = recbuf[i];
        const unsigned long long pay = paybuf[i];
        const int p = atomicAdd(&lcur[r >> 21], 1);
        inv[p]   = (int)(r & 0x1FFFFFu);
        src_s[p] = (unsigned short)(pay >> 21);
        rvt[p]   = (int)(pay & 0x1FFFFFu);
    }
}

// ---------------------------------------------------------------------------
// bin2: route (p, e=inv[p]) records into e-bucket runs (u64 records).
// ---------------------------------------------------------------------------
__global__ void __launch_bounds__(256) bin2_kernel(
    const int* __restrict__ inv, int* __restrict__ gcur2,
    unsigned long long* __restrict__ recbuf2)
{
    __shared__ int hist[kNB];
    __shared__ int sh[kNB];
    __shared__ int cursor[kNB];
    __shared__ int gdbase[kNB];
    __shared__ unsigned long long buf[kChunk];

    const int tid = threadIdx.x;
    const int p0  = blockIdx.x * kChunk;
    const int n   = (kE - p0 < kChunk) ? (kE - p0) : kChunk;

    hist[tid] = 0;
    __syncthreads();

    int myb[16];
    unsigned long long rec[16];
#pragma unroll
    for (int k = 0; k < 16; ++k) {
        const int i = tid + k * 256;
        myb[k] = -1;
        if (i < n) {
            const int e = inv[p0 + i];
            const int b = e / kEperB;
            myb[k] = b;
            rec[k] = ((unsigned long long)(e - b * kEperB) << 32) | (unsigned int)(p0 + i);
            atomicAdd(&hist[b], 1);
        }
    }
    __syncthreads();

    const int cnt = hist[tid];
    sh[tid] = cnt;
    __syncthreads();
#pragma unroll
    for (int off = 1; off < kNB; off <<= 1) {
        int t = (tid >= off) ? sh[tid - off] : 0;
        __syncthreads();
        sh[tid] += t;
        __syncthreads();
    }
    const int excl = sh[tid] - cnt;
    cursor[tid] = excl;
    __syncthreads();

#pragma unroll
    for (int k = 0; k < 16; ++k) {
        if (myb[k] >= 0) {
            int slot = atomicAdd(&cursor[myb[k]], 1);
            buf[slot] = rec[k];
        }
    }
    gdbase[tid] = (cnt > 0) ? atomicAdd(&gcur2[tid], cnt) : 0;
    __syncthreads();

    for (int i = tid; i < n; i += 256) {
        int b = 0;
#pragma unroll
        for (int step = 128; step >= 1; step >>= 1)
            if (b + step <= kNB - 1 && sh[b + step - 1] <= i) b += step;
        const int off_in_b = i - (sh[b] - hist[b]);
        recbuf2[gdbase[b] + off_in_b] = buf[i];
    }
}

// ---------------------------------------------------------------------------
// fine2: per e-bucket, slot[e_local] = p, write spos contiguously.
// ---------------------------------------------------------------------------
__global__ void __launch_bounds__(256) fine2_kernel(
    const unsigned long long* __restrict__ recbuf2, int* __restrict__ spos)
{
    __shared__ int slot[kEperB];
    const int tid  = threadIdx.x;
    const int base = blockIdx.x * kEperB;

    for (int i = tid; i < kEperB; i += 256) {
        const unsigned long long r = recbuf2[base + i];
        slot[(int)(r >> 32)] = (int)(r & 0xFFFFFFFFu);
    }
    __syncthreads();
    for (int i = tid; i < kEperB; i += 256)
        spos[base + i] = slot[i];
}

// ---------------------------------------------------------------------------
// build: rv_s[p] = spos[rvt[p]]  (contig read, one L2/L3 gather, contig write)
// ---------------------------------------------------------------------------
__global__ void __launch_bounds__(256) build_kernel(
    const int* __restrict__ rvt, const int* __restrict__ spos,
    int* __restrict__ rv_s)
{
    const int p0 = (blockIdx.x * 256 + threadIdx.x) * 2;
    if (p0 >= kE) return;
    const int2 rr = *reinterpret_cast<const int2*>(rvt + p0);
    *reinterpret_cast<int2*>(rv_s + p0) = make_int2(spos[rr.x], spos[rr.y]);
}

// ---------------------------------------------------------------------------
// Edge kernel, DST-SORTED order, 2 edges/thread.
// ---------------------------------------------------------------------------
template <bool FIRST>
__global__ void __launch_bounds__(256) edge_kernel(
    const unsigned short* __restrict__ src_s, const int* __restrict__ rv_s,
    const float* __restrict__ log_b,
    const unsigned short* __restrict__ mold,
    unsigned short* __restrict__ mnew)
{
    const int i0 = (blockIdx.x * 256 + threadIdx.x) * 2;
    if (i0 >= kE) return;

    const ushort2 sp = *reinterpret_cast<const ushort2*>(src_s + i0);

    const float4* lba = reinterpret_cast<const float4*>(log_b + (size_t)sp.x * 8);
    const float4* lbb = reinterpret_cast<const float4*>(log_b + (size_t)sp.y * 8);
    float4 a0 = lba[0], a1 = lba[1];
    float4 b0 = lbb[0], b1 = lbb[1];

    uint4 ma, mb;
    if (!FIRST) {
        const int2 rp = *reinterpret_cast<const int2*>(rv_s + i0);
        ma = *reinterpret_cast<const uint4*>(mold + (size_t)rp.x * 8);
        mb = *reinterpret_cast<const uint4*>(mold + (size_t)rp.y * 8);
    }

    float ta[8] = {a0.x, a0.y, a0.z, a0.w, a1.x, a1.y, a1.z, a1.w};
    float tb[8] = {b0.x, b0.y, b0.z, b0.w, b1.x, b1.y, b1.z, b1.w};
    if (!FIRST) {
        ta[0] -= (float)(ma.x & 0xffffu) * kDEC;  ta[1] -= (float)(ma.x >> 16) * kDEC;
        ta[2] -= (float)(ma.y & 0xffffu) * kDEC;  ta[3] -= (float)(ma.y >> 16) * kDEC;
        ta[4] -= (float)(ma.z & 0xffffu) * kDEC;  ta[5] -= (float)(ma.z >> 16) * kDEC;
        ta[6] -= (float)(ma.w & 0xffffu) * kDEC;  ta[7] -= (float)(ma.w >> 16) * kDEC;
        tb[0] -= (float)(mb.x & 0xffffu) * kDEC;  tb[1] -= (float)(mb.x >> 16) * kDEC;
        tb[2] -= (float)(mb.y & 0xffffu) * kDEC;  tb[3] -= (float)(mb.y >> 16) * kDEC;
        tb[4] -= (float)(mb.z & 0xffffu) * kDEC;  tb[5] -= (float)(mb.z >> 16) * kDEC;
        tb[6] -= (float)(mb.w & 0xffffu) * kDEC;  tb[7] -= (float)(mb.w >> 16) * kDEC;
    }

    unsigned int qa[8], qb[8];
    {
        float mx = ta[0];
#pragma unroll
        for (int c = 1; c < 8; ++c) mx = fmaxf(mx, ta[c]);
        float p[8], S = 0.f;
#pragma unroll
        for (int c = 0; c < 8; ++c) { p[c] = __expf(ta[c] - mx); S += p[c]; }
        const float coef = kOneMA / S;
#pragma unroll
        for (int c = 0; c < 8; ++c) {
            float u  = fmaf(coef, p[c], kA);
            float qq = fmaf(__logf(u), kENC, 65535.0f);
            qq = fminf(fmaxf(qq + 0.5f, 0.0f), 65535.0f);
            qa[c] = (unsigned int)qq;
        }
    }
    {
        float mx = tb[0];
#pragma unroll
        for (int c = 1; c < 8; ++c) mx = fmaxf(mx, tb[c]);
        float p[8], S = 0.f;
#pragma unroll
        for (int c = 0; c < 8; ++c) { p[c] = __expf(tb[c] - mx); S += p[c]; }
        const float coef = kOneMA / S;
#pragma unroll
        for (int c = 0; c < 8; ++c) {
            float u  = fmaf(coef, p[c], kA);
            float qq = fmaf(__logf(u), kENC, 65535.0f);
            qq = fminf(fmaxf(qq + 0.5f, 0.0f), 65535.0f);
            qb[c] = (unsigned int)qq;
        }
    }

    uint4* mn = reinterpret_cast<uint4*>(mnew + (size_t)i0 * 8);
    mn[0] = make_uint4(qa[0] | (qa[1] << 16), qa[2] | (qa[3] << 16),
                       qa[4] | (qa[5] << 16), qa[6] | (qa[7] << 16));
    mn[1] = make_uint4(qb[0] | (qb[1] << 16), qb[2] | (qb[3] << 16),
                       qb[4] | (qb[5] << 16), qb[6] | (qb[7] << 16));
}

// ---------------------------------------------------------------------------
// Node kernel: 2 nodes/wave, streaming contiguous msg runs (exact int sum).
// Normalize only on FINAL step (softmax shift-invariant).
// ---------------------------------------------------------------------------
template <bool FINAL>
__global__ void __launch_bounds__(256) node_kernel(
    const int* __restrict__ start,
    const unsigned short* __restrict__ msgq,
    const float* __restrict__ log_b0, float* __restrict__ log_b)
{
    const int wid  = (blockIdx.x * 256 + threadIdx.x) >> 6;
    const int lane = threadIdx.x & 63;
    const int half = lane >> 5;
    const int l32  = lane & 31;
    const int n = wid * 2 + half;
    if (n >= kN) return;

    const int s = start[n], e2 = start[n + 1];

    int q[8] = {0, 0, 0, 0, 0, 0, 0, 0};
    for (int j = s + l32; j < e2; j += 32) {
        const uint4 m = *reinterpret_cast<const uint4*>(msgq + (size_t)j * 8);
        q[0] += (int)(m.x & 0xffffu);  q[1] += (int)(m.x >> 16);
        q[2] += (int)(m.y & 0xffffu);  q[3] += (int)(m.y >> 16);
        q[4] += (int)(m.z & 0xffffu);  q[5] += (int)(m.z >> 16);
        q[6] += (int)(m.w & 0xffffu);  q[7] += (int)(m.w >> 16);
    }
#pragma unroll
    for (int off = 1; off <= 16; off <<= 1) {
#pragma unroll
        for (int c = 0; c < 8; ++c) q[c] += __shfl_xor(q[c], off, 64);
    }

    if (l32 == 0) {
        const int deg = e2 - s;
        const float base = -kOFF * (float)deg;
        const float4* lb0 = reinterpret_cast<const float4*>(log_b0 + (size_t)n * 8);
        float4 c0 = lb0[0], c1 = lb0[1];
        float v[8];
        v[0] = fmaf((float)q[0], kDEC, base) + c0.x;
        v[1] = fmaf((float)q[1], kDEC, base) + c0.y;
        v[2] = fmaf((float)q[2], kDEC, base) + c0.z;
        v[3] = fmaf((float)q[3], kDEC, base) + c0.w;
        v[4] = fmaf((float)q[4], kDEC, base) + c1.x;
        v[5] = fmaf((float)q[5], kDEC, base) + c1.y;
        v[6] = fmaf((float)q[6], kDEC, base) + c1.z;
        v[7] = fmaf((float)q[7], kDEC, base) + c1.w;
        if (FINAL) {
            float m = v[0];
#pragma unroll
            for (int c = 1; c < 8; ++c) m = fmaxf(m, v[c]);
            float sum = 0.f;
#pragma unroll
            for (int c = 0; c < 8; ++c) sum += __expf(v[c] - m);
            float lse = m + __logf(sum);
#pragma unroll
            for (int c = 0; c < 8; ++c) v[c] -= lse;
        }
        float4* lb = reinterpret_cast<float4*>(log_b + (size_t)n * 8);
        lb[0] = make_float4(v[0], v[1], v[2], v[3]);
        lb[1] = make_float4(v[4], v[5], v[6], v[7]);
    }
}

extern "C" void kernel_launch(void* const* d_in, const int* in_sizes, int n_in,
                              void* d_out, int out_size, void* d_ws, size_t ws_size,
                              hipStream_t stream) {
    const float* x    = (const float*)d_in[0];
    const float* W    = (const float*)d_in[1];
    const float* bias = (const float*)d_in[2];
    const int*   ei   = (const int*)d_in[3];
    const int*   rv   = (const int*)d_in[4];
    const int* src = ei;
    const int* dst = ei + kE;
    float* out = (float*)d_out;

    if (ws_size < WS_NEEDED) return;

    char* ws = (char*)d_ws;
    float* log_b0 = (float*)(ws + OFF_LOGB0);
    int*   bhist  = (int*)(ws + OFF_BHIST);
    int*   gbase  = (int*)(ws + OFF_GBASE);
    int*   gcur   = (int*)(ws + OFF_GCUR);
    int*   start  = (int*)(ws + OFF_START);
    unsigned int*       recbuf = (unsigned int*)(ws + OFF_REC);
    unsigned long long* paybuf = (unsigned long long*)(ws + OFF_PAY);
    int*   inv    = (int*)(ws + OFF_INV);
    unsigned short* msgA = (unsigned short*)(ws + OFF_MSGA);
    unsigned short* msgB = (unsigned short*)(ws + OFF_MSGB);
    int*   spos   = (int*)(ws + OFF_SPOS);
    unsigned short* src_s = (unsigned short*)(ws + OFF_SRCS);
    int*   rvt    = (int*)(ws + OFF_RVT);
    int*   rv_s   = (int*)(ws + OFF_RVS);
    unsigned long long* recbuf2 = (unsigned long long*)(ws + OFF_REC2);
    int*   gcur2  = (int*)(ws + OFF_GCUR2);

    const int edgeBlocks = (kE / 2 + 255) / 256;            // 3125
    const int nodeBlocks = ((kN + 1) / 2 * 64 + 255) / 256; // 6250
    const int binBlocks  = (kE + kChunk - 1) / kChunk;      // 391

    (void)hipMemsetAsync(bhist, 0, kNB * sizeof(int), stream);
    init_kernel<<<1280, 256, 0, stream>>>(x, W, bias, log_b0, out, dst, bhist);
    bucket_scan_kernel<<<1, 256, 0, stream>>>(bhist, gbase, gcur, gcur2);
    bin_kernel<<<binBlocks, 256, 0, stream>>>(dst, src, rv, gcur, recbuf, paybuf);
    fine_kernel<<<kNB, 256, 0, stream>>>(gbase, recbuf, paybuf, start, inv, src_s, rvt);
    bin2_kernel<<<binBlocks, 256, 0, stream>>>(inv, gcur2, recbuf2);
    fine2_kernel<<<kNB, 256, 0, stream>>>(recbuf2, spos);
    build_kernel<<<edgeBlocks, 256, 0, stream>>>(rvt, spos, rv_s);

    // step 0 (uniform initial msg cancels in softmax)
    edge_kernel<true><<<edgeBlocks, 256, 0, stream>>>(src_s, rv_s, out, msgB, msgA);
    node_kernel<false><<<nodeBlocks, 256, 0, stream>>>(start, msgA, log_b0, out);

    unsigned short* cur = msgA;
    unsigned short* nxt = msgB;
    for (int it = 1; it < kSteps; ++it) {
        edge_kernel<false><<<edgeBlocks, 256, 0, stream>>>(src_s, rv_s, out, cur, nxt);
        if (it == kSteps - 1)
            node_kernel<true><<<nodeBlocks, 256, 0, stream>>>(start, nxt, log_b0, out);
        else
            node_kernel<false><<<nodeBlocks, 256, 0, stream>>>(start, nxt, log_b0, out);
        unsigned short* tmp = cur; cur = nxt; nxt = tmp;
    }
}

// Round 10
// 453.425 us; speedup vs baseline: 1.1157x; 1.0382x over previous
//
#include <hip/hip_runtime.h>

static constexpr int kN   = 50000;
static constexpr int kDin = 256;
static constexpr int kC   = 8;
static constexpr int kE   = 1600000;
static constexpr int kSteps = 5;

static constexpr int kNB      = 256;   // coarse buckets
static constexpr int kBucketW = 196;   // nodes per bucket (196*256 >= 50000)
static constexpr int kChunk   = 4096;  // edges per bin block
static constexpr int kEperB   = kE / kNB;  // 6250 edges per e-bucket (exact)

// ---------------- ws layout (bytes) ----------------
static constexpr size_t OFF_LOGB0 = 0;            // kN*8*4  = 1,600,000
static constexpr size_t OFF_BHIST = 1600000;      // 256*4
static constexpr size_t OFF_GBASE = 1601024;      // 257*4 -> pad
static constexpr size_t OFF_GCUR  = 1602112;      // 257*4 -> pad
static constexpr size_t OFF_START = 1603200;      // (kN+1)*4
static constexpr size_t OFF_REC   = 1803264;      // kE*4  = 6,400,000
static constexpr size_t OFF_PAY   = 8203264;      // kE*8  = 12,800,000
static constexpr size_t OFF_INV   = 21003264;     // kE*4
static constexpr size_t OFF_MSGA  = 27403264;     // kE*8 (u8)  = 12,800,000
static constexpr size_t OFF_MSGB  = 40203264;     // kE*8 (u8)  = 12,800,000
static constexpr size_t OFF_SPOS  = 53003264;     // kE*4
static constexpr size_t OFF_SRCS  = 59403264;     // kE*2 (u16)
static constexpr size_t OFF_RVT   = 62603264;     // kE*4
static constexpr size_t OFF_RVS   = 69003264;     // kE*4
static constexpr size_t OFF_REC2  = 75403264;     // kE*8
static constexpr size_t OFF_GCUR2 = 88203264;     // 256*4
static constexpr size_t WS_NEEDED = 88204288;

// msg quantization (u8): o = log((1-A)p + A) - K in [-3-K, -K], width exactly 3
// q = round((o + 3 + K) * 255/3); decode o = q*(3/255) - (3+K)
static constexpr float kDEC8  = 3.0f / 255.0f;         // 0.011764706
static constexpr float kENC8  = 255.0f / 3.0f;         // 85.0
static constexpr float kOFF   = 3.2990003f;            // 3 + K
static constexpr float kA     = 0.049787068367863944f; // e^-3
static constexpr float kOneMA = 0.950212931632136f;    // 1 - A

// ---------------------------------------------------------------------------
// Fused init: blocks [0,1024) phase1 (log_b0 = log_softmax(xW+b)),
//             blocks [1024,1280) coarse dst-bucket histogram.
// ---------------------------------------------------------------------------
__global__ void __launch_bounds__(256) init_kernel(
    const float* __restrict__ x, const float* __restrict__ W,
    const float* __restrict__ bias,
    float* __restrict__ log_b0, float* __restrict__ log_b,
    const int* __restrict__ dst, int* __restrict__ bhist)
{
    __shared__ int h[kNB];
    if (blockIdx.x >= 1024) {
        h[threadIdx.x] = 0;
        __syncthreads();
        const int nthr = 256 * 256;
        for (int e = (blockIdx.x - 1024) * 256 + threadIdx.x; e < kE; e += nthr)
            atomicAdd(&h[dst[e] / kBucketW], 1);
        __syncthreads();
        if (h[threadIdx.x]) atomicAdd(&bhist[threadIdx.x], h[threadIdx.x]);
        return;
    }

    const int lane   = threadIdx.x & 63;
    const int wave   = (blockIdx.x * 256 + threadIdx.x) >> 6;
    const int nwaves = (1024 * 256) >> 6;

    float w[4][8];
#pragma unroll
    for (int j = 0; j < 4; ++j) {
        const float4* wp = reinterpret_cast<const float4*>(W + (size_t)(lane + 64 * j) * kC);
        float4 a = wp[0], b2 = wp[1];
        w[j][0] = a.x;  w[j][1] = a.y;  w[j][2] = a.z;  w[j][3] = a.w;
        w[j][4] = b2.x; w[j][5] = b2.y; w[j][6] = b2.z; w[j][7] = b2.w;
    }

    for (int row = wave; row < kN; row += nwaves) {
        const float* xr = x + (size_t)row * kDin;
        float acc[8] = {0.f, 0.f, 0.f, 0.f, 0.f, 0.f, 0.f, 0.f};
#pragma unroll
        for (int j = 0; j < 4; ++j) {
            float xv = xr[lane + 64 * j];
#pragma unroll
            for (int c = 0; c < 8; ++c) acc[c] = fmaf(xv, w[j][c], acc[c]);
        }
#pragma unroll
        for (int off = 32; off > 0; off >>= 1) {
#pragma unroll
            for (int c = 0; c < 8; ++c) acc[c] += __shfl_down(acc[c], off, 64);
        }
        if (lane == 0) {
            float z[8], m = -1e30f;
#pragma unroll
            for (int c = 0; c < 8; ++c) { z[c] = acc[c] + bias[c]; m = fmaxf(m, z[c]); }
            float s = 0.f;
#pragma unroll
            for (int c = 0; c < 8; ++c) s += __expf(z[c] - m);
            float lse = m + __logf(s);
#pragma unroll
            for (int c = 0; c < 8; ++c) {
                float v = z[c] - lse;
                log_b0[(size_t)row * 8 + c] = v;
                log_b[(size_t)row * 8 + c]  = v;
            }
        }
    }
}

// ---------------------------------------------------------------------------
// scan 256 dst-bucket counts -> gbase/gcur; also init gcur2 (uniform buckets)
// ---------------------------------------------------------------------------
__global__ void __launch_bounds__(256) bucket_scan_kernel(
    const int* __restrict__ bhist, int* __restrict__ gbase, int* __restrict__ gcur,
    int* __restrict__ gcur2)
{
    __shared__ int sh[kNB];
    const int tid = threadIdx.x;
    int v = bhist[tid];
    sh[tid] = v;
    __syncthreads();
#pragma unroll
    for (int off = 1; off < kNB; off <<= 1) {
        int t = (tid >= off) ? sh[tid - off] : 0;
        __syncthreads();
        sh[tid] += t;
        __syncthreads();
    }
    int excl = sh[tid] - v;
    gbase[tid] = excl;
    gcur[tid]  = excl;
    gcur2[tid] = tid * kEperB;
    if (tid == kNB - 1) { gbase[kNB] = sh[tid]; gcur[kNB] = sh[tid]; }
}

// ---------------------------------------------------------------------------
// bin: 4096-edge chunks -> dst-bucket-contiguous runs.
//   key u32 = local(8b)<<21 | e(21b);  pay u64 = src(16b)<<21 | rv(21b)
// ---------------------------------------------------------------------------
__global__ void __launch_bounds__(256) bin_kernel(
    const int* __restrict__ dst, const int* __restrict__ src,
    const int* __restrict__ rv, int* __restrict__ gcur,
    unsigned int* __restrict__ recbuf, unsigned long long* __restrict__ paybuf)
{
    __shared__ int hist[kNB];
    __shared__ int sh[kNB];
    __shared__ int cursor[kNB];
    __shared__ int gdbase[kNB];
    __shared__ unsigned int buf[kChunk];
    __shared__ unsigned long long pbuf[kChunk];

    const int tid = threadIdx.x;
    const int e0  = blockIdx.x * kChunk;
    const int n   = (kE - e0 < kChunk) ? (kE - e0) : kChunk;

    hist[tid] = 0;
    __syncthreads();

    int myb[16];
    unsigned int rec[16];
    unsigned long long pay[16];
#pragma unroll
    for (int k = 0; k < 16; ++k) {
        const int i = tid + k * 256;
        myb[k] = -1;
        if (i < n) {
            const int d = dst[e0 + i];
            const int b = d / kBucketW;
            myb[k] = b;
            rec[k] = ((unsigned int)(d - b * kBucketW) << 21) | (unsigned int)(e0 + i);
            pay[k] = ((unsigned long long)(unsigned int)src[e0 + i] << 21)
                   | (unsigned int)rv[e0 + i];
            atomicAdd(&hist[b], 1);
        }
    }
    __syncthreads();

    const int cnt = hist[tid];
    sh[tid] = cnt;
    __syncthreads();
#pragma unroll
    for (int off = 1; off < kNB; off <<= 1) {
        int t = (tid >= off) ? sh[tid - off] : 0;
        __syncthreads();
        sh[tid] += t;
        __syncthreads();
    }
    const int excl = sh[tid] - cnt;
    cursor[tid] = excl;
    __syncthreads();

#pragma unroll
    for (int k = 0; k < 16; ++k) {
        if (myb[k] >= 0) {
            int slot = atomicAdd(&cursor[myb[k]], 1);
            buf[slot]  = rec[k];
            pbuf[slot] = pay[k];
        }
    }
    gdbase[tid] = (cnt > 0) ? atomicAdd(&gcur[tid], cnt) : 0;
    __syncthreads();

    for (int i = tid; i < n; i += 256) {
        int b = 0;
#pragma unroll
        for (int step = 128; step >= 1; step >>= 1)
            if (b + step <= kNB - 1 && sh[b + step - 1] <= i) b += step;
        const int off_in_b = i - (sh[b] - hist[b]);
        recbuf[gdbase[b] + off_in_b] = buf[i];
        paybuf[gdbase[b] + off_in_b] = pbuf[i];
    }
}

// ---------------------------------------------------------------------------
// fine: per dst-bucket counting sort -> start[], inv[], src_s[] (u16), rvt[]
// ---------------------------------------------------------------------------
__global__ void __launch_bounds__(256) fine_kernel(
    const int* __restrict__ gbase, const unsigned int* __restrict__ recbuf,
    const unsigned long long* __restrict__ paybuf,
    int* __restrict__ start, int* __restrict__ inv,
    unsigned short* __restrict__ src_s, int* __restrict__ rvt)
{
    __shared__ int hist[kNB];
    __shared__ int sh[kNB];
    __shared__ int lcur[kNB];

    const int tid = threadIdx.x;
    const int b   = blockIdx.x;
    const int nb0 = b * kBucketW;
    const int nnode = (kN - nb0 < kBucketW) ? (kN - nb0) : kBucketW;
    const int rb = gbase[b], re = gbase[b + 1];

    hist[tid] = 0;
    __syncthreads();

    for (int i = rb + tid; i < re; i += 256)
        atomicAdd(&hist[recbuf[i] >> 21], 1);
    __syncthreads();

    const int cnt = hist[tid];
    sh[tid] = cnt;
    __syncthreads();
#pragma unroll
    for (int off = 1; off < kNB; off <<= 1) {
        int t = (tid >= off) ? sh[tid - off] : 0;
        __syncthreads();
        sh[tid] += t;
        __syncthreads();
    }
    const int excl = sh[tid] - cnt;
    lcur[tid] = rb + excl;
    if (tid < nnode) start[nb0 + tid] = rb + excl;
    if (b == gridDim.x - 1 && tid == 0) start[kN] = kE;
    __syncthreads();

    for (int i = rb + tid; i < re; i += 256) {
        const unsigned int r = recbuf[i];
        const unsigned long long pay = paybuf[i];
        const int p = atomicAdd(&lcur[r >> 21], 1);
        inv[p]   = (int)(r & 0x1FFFFFu);
        src_s[p] = (unsigned short)(pay >> 21);
        rvt[p]   = (int)(pay & 0x1FFFFFu);
    }
}

// ---------------------------------------------------------------------------
// bin2: route (p, e=inv[p]) records into e-bucket runs (u64 records).
// ---------------------------------------------------------------------------
__global__ void __launch_bounds__(256) bin2_kernel(
    const int* __restrict__ inv, int* __restrict__ gcur2,
    unsigned long long* __restrict__ recbuf2)
{
    __shared__ int hist[kNB];
    __shared__ int sh[kNB];
    __shared__ int cursor[kNB];
    __shared__ int gdbase[kNB];
    __shared__ unsigned long long buf[kChunk];

    const int tid = threadIdx.x;
    const int p0  = blockIdx.x * kChunk;
    const int n   = (kE - p0 < kChunk) ? (kE - p0) : kChunk;

    hist[tid] = 0;
    __syncthreads();

    int myb[16];
    unsigned long long rec[16];
#pragma unroll
    for (int k = 0; k < 16; ++k) {
        const int i = tid + k * 256;
        myb[k] = -1;
        if (i < n) {
            const int e = inv[p0 + i];
            const int b = e / kEperB;
            myb[k] = b;
            rec[k] = ((unsigned long long)(e - b * kEperB) << 32) | (unsigned int)(p0 + i);
            atomicAdd(&hist[b], 1);
        }
    }
    __syncthreads();

    const int cnt = hist[tid];
    sh[tid] = cnt;
    __syncthreads();
#pragma unroll
    for (int off = 1; off < kNB; off <<= 1) {
        int t = (tid >= off) ? sh[tid - off] : 0;
        __syncthreads();
        sh[tid] += t;
        __syncthreads();
    }
    const int excl = sh[tid] - cnt;
    cursor[tid] = excl;
    __syncthreads();

#pragma unroll
    for (int k = 0; k < 16; ++k) {
        if (myb[k] >= 0) {
            int slot = atomicAdd(&cursor[myb[k]], 1);
            buf[slot] = rec[k];
        }
    }
    gdbase[tid] = (cnt > 0) ? atomicAdd(&gcur2[tid], cnt) : 0;
    __syncthreads();

    for (int i = tid; i < n; i += 256) {
        int b = 0;
#pragma unroll
        for (int step = 128; step >= 1; step >>= 1)
            if (b + step <= kNB - 1 && sh[b + step - 1] <= i) b += step;
        const int off_in_b = i - (sh[b] - hist[b]);
        recbuf2[gdbase[b] + off_in_b] = buf[i];
    }
}

// ---------------------------------------------------------------------------
// fine2: per e-bucket, slot[e_local] = p, write spos contiguously.
// ---------------------------------------------------------------------------
__global__ void __launch_bounds__(256) fine2_kernel(
    const unsigned long long* __restrict__ recbuf2, int* __restrict__ spos)
{
    __shared__ int slot[kEperB];
    const int tid  = threadIdx.x;
    const int base = blockIdx.x * kEperB;

    for (int i = tid; i < kEperB; i += 256) {
        const unsigned long long r = recbuf2[base + i];
        slot[(int)(r >> 32)] = (int)(r & 0xFFFFFFFFu);
    }
    __syncthreads();
    for (int i = tid; i < kEperB; i += 256)
        spos[base + i] = slot[i];
}

// ---------------------------------------------------------------------------
// build: rv_s[p] = spos[rvt[p]]
// ---------------------------------------------------------------------------
__global__ void __launch_bounds__(256) build_kernel(
    const int* __restrict__ rvt, const int* __restrict__ spos,
    int* __restrict__ rv_s)
{
    const int p0 = (blockIdx.x * 256 + threadIdx.x) * 2;
    if (p0 >= kE) return;
    const int2 rr = *reinterpret_cast<const int2*>(rvt + p0);
    *reinterpret_cast<int2*>(rv_s + p0) = make_int2(spos[rr.x], spos[rr.y]);
}

// ---------------------------------------------------------------------------
// per-edge softmax + u8 encode (fully unrolled, register-resident)
// ---------------------------------------------------------------------------
template <bool FIRST>
__device__ inline uint2 proc_edge(float4 l0, float4 l1, uint2 m)
{
    float t[8] = {l0.x, l0.y, l0.z, l0.w, l1.x, l1.y, l1.z, l1.w};
    if (!FIRST) {
        t[0] -= (float)(m.x & 0xffu)         * kDEC8;
        t[1] -= (float)((m.x >> 8) & 0xffu)  * kDEC8;
        t[2] -= (float)((m.x >> 16) & 0xffu) * kDEC8;
        t[3] -= (float)(m.x >> 24)           * kDEC8;
        t[4] -= (float)(m.y & 0xffu)         * kDEC8;
        t[5] -= (float)((m.y >> 8) & 0xffu)  * kDEC8;
        t[6] -= (float)((m.y >> 16) & 0xffu) * kDEC8;
        t[7] -= (float)(m.y >> 24)           * kDEC8;
    }
    float mx = t[0];
#pragma unroll
    for (int c = 1; c < 8; ++c) mx = fmaxf(mx, t[c]);
    float p[8], S = 0.f;
#pragma unroll
    for (int c = 0; c < 8; ++c) { p[c] = __expf(t[c] - mx); S += p[c]; }
    const float coef = kOneMA / S;
    unsigned int q[8];
#pragma unroll
    for (int c = 0; c < 8; ++c) {
        float u  = fmaf(coef, p[c], kA);                 // in [A, ~1]
        float qq = fmaf(__logf(u), kENC8, 255.0f);       // (log(u)+3)*255/3
        qq = fminf(fmaxf(qq + 0.5f, 0.0f), 255.0f);
        q[c] = (unsigned int)qq;
    }
    return make_uint2(q[0] | (q[1] << 8) | (q[2] << 16) | (q[3] << 24),
                      q[4] | (q[5] << 8) | (q[6] << 16) | (q[7] << 24));
}

// ---------------------------------------------------------------------------
// Edge kernel, DST-SORTED order, 4 edges/thread (all gathers issued up front).
// ---------------------------------------------------------------------------
template <bool FIRST>
__global__ void __launch_bounds__(256) edge_kernel(
    const unsigned short* __restrict__ src_s, const int* __restrict__ rv_s,
    const float* __restrict__ log_b,
    const unsigned char* __restrict__ mold,
    unsigned char* __restrict__ mnew)
{
    const int i0 = (blockIdx.x * 256 + threadIdx.x) * 4;
    if (i0 >= kE) return;

    const ushort4 sp = *reinterpret_cast<const ushort4*>(src_s + i0);

    const float4* pa = reinterpret_cast<const float4*>(log_b + (size_t)sp.x * 8);
    const float4* pb = reinterpret_cast<const float4*>(log_b + (size_t)sp.y * 8);
    const float4* pc = reinterpret_cast<const float4*>(log_b + (size_t)sp.z * 8);
    const float4* pd = reinterpret_cast<const float4*>(log_b + (size_t)sp.w * 8);
    float4 a0 = pa[0], a1 = pa[1];
    float4 b0 = pb[0], b1 = pb[1];
    float4 c0 = pc[0], c1 = pc[1];
    float4 d0 = pd[0], d1 = pd[1];

    uint2 m0 = make_uint2(0, 0), m1 = m0, m2 = m0, m3 = m0;
    if (!FIRST) {
        const int4 rp = *reinterpret_cast<const int4*>(rv_s + i0);
        m0 = *reinterpret_cast<const uint2*>(mold + (size_t)rp.x * 8);
        m1 = *reinterpret_cast<const uint2*>(mold + (size_t)rp.y * 8);
        m2 = *reinterpret_cast<const uint2*>(mold + (size_t)rp.z * 8);
        m3 = *reinterpret_cast<const uint2*>(mold + (size_t)rp.w * 8);
    }

    const uint2 o0 = proc_edge<FIRST>(a0, a1, m0);
    const uint2 o1 = proc_edge<FIRST>(b0, b1, m1);
    const uint2 o2 = proc_edge<FIRST>(c0, c1, m2);
    const uint2 o3 = proc_edge<FIRST>(d0, d1, m3);

    uint4* mn = reinterpret_cast<uint4*>(mnew + (size_t)i0 * 8);
    mn[0] = make_uint4(o0.x, o0.y, o1.x, o1.y);
    mn[1] = make_uint4(o2.x, o2.y, o3.x, o3.y);
}

// ---------------------------------------------------------------------------
// Node kernel: 2 nodes/wave, streaming contiguous u8 msg runs (exact int sum).
// Normalize only on FINAL step (softmax shift-invariant).
// ---------------------------------------------------------------------------
template <bool FINAL>
__global__ void __launch_bounds__(256) node_kernel(
    const int* __restrict__ start,
    const unsigned char* __restrict__ msgq,
    const float* __restrict__ log_b0, float* __restrict__ log_b)
{
    const int wid  = (blockIdx.x * 256 + threadIdx.x) >> 6;
    const int lane = threadIdx.x & 63;
    const int half = lane >> 5;
    const int l32  = lane & 31;
    const int n = wid * 2 + half;
    if (n >= kN) return;

    const int s = start[n], e2 = start[n + 1];

    int q[8] = {0, 0, 0, 0, 0, 0, 0, 0};
    for (int j = s + l32; j < e2; j += 32) {
        const uint2 m = *reinterpret_cast<const uint2*>(msgq + (size_t)j * 8);
        q[0] += (int)(m.x & 0xffu);          q[1] += (int)((m.x >> 8) & 0xffu);
        q[2] += (int)((m.x >> 16) & 0xffu);  q[3] += (int)(m.x >> 24);
        q[4] += (int)(m.y & 0xffu);          q[5] += (int)((m.y >> 8) & 0xffu);
        q[6] += (int)((m.y >> 16) & 0xffu);  q[7] += (int)(m.y >> 24);
    }
#pragma unroll
    for (int off = 1; off <= 16; off <<= 1) {
#pragma unroll
        for (int c = 0; c < 8; ++c) q[c] += __shfl_xor(q[c], off, 64);
    }

    if (l32 == 0) {
        const int deg = e2 - s;
        const float base = -kOFF * (float)deg;
        const float4* lb0 = reinterpret_cast<const float4*>(log_b0 + (size_t)n * 8);
        float4 c0 = lb0[0], c1 = lb0[1];
        float v[8];
        v[0] = fmaf((float)q[0], kDEC8, base) + c0.x;
        v[1] = fmaf((float)q[1], kDEC8, base) + c0.y;
        v[2] = fmaf((float)q[2], kDEC8, base) + c0.z;
        v[3] = fmaf((float)q[3], kDEC8, base) + c0.w;
        v[4] = fmaf((float)q[4], kDEC8, base) + c1.x;
        v[5] = fmaf((float)q[5], kDEC8, base) + c1.y;
        v[6] = fmaf((float)q[6], kDEC8, base) + c1.z;
        v[7] = fmaf((float)q[7], kDEC8, base) + c1.w;
        if (FINAL) {
            float m = v[0];
#pragma unroll
            for (int c = 1; c < 8; ++c) m = fmaxf(m, v[c]);
            float sum = 0.f;
#pragma unroll
            for (int c = 0; c < 8; ++c) sum += __expf(v[c] - m);
            float lse = m + __logf(sum);
#pragma unroll
            for (int c = 0; c < 8; ++c) v[c] -= lse;
        }
        float4* lb = reinterpret_cast<float4*>(log_b + (size_t)n * 8);
        lb[0] = make_float4(v[0], v[1], v[2], v[3]);
        lb[1] = make_float4(v[4], v[5], v[6], v[7]);
    }
}

extern "C" void kernel_launch(void* const* d_in, const int* in_sizes, int n_in,
                              void* d_out, int out_size, void* d_ws, size_t ws_size,
                              hipStream_t stream) {
    const float* x    = (const float*)d_in[0];
    const float* W    = (const float*)d_in[1];
    const float* bias = (const float*)d_in[2];
    const int*   ei   = (const int*)d_in[3];
    const int*   rv   = (const int*)d_in[4];
    const int* src = ei;
    const int* dst = ei + kE;
    float* out = (float*)d_out;

    if (ws_size < WS_NEEDED) return;

    char* ws = (char*)d_ws;
    float* log_b0 = (float*)(ws + OFF_LOGB0);
    int*   bhist  = (int*)(ws + OFF_BHIST);
    int*   gbase  = (int*)(ws + OFF_GBASE);
    int*   gcur   = (int*)(ws + OFF_GCUR);
    int*   start  = (int*)(ws + OFF_START);
    unsigned int*       recbuf = (unsigned int*)(ws + OFF_REC);
    unsigned long long* paybuf = (unsigned long long*)(ws + OFF_PAY);
    int*   inv    = (int*)(ws + OFF_INV);
    unsigned char* msgA = (unsigned char*)(ws + OFF_MSGA);
    unsigned char* msgB = (unsigned char*)(ws + OFF_MSGB);
    int*   spos   = (int*)(ws + OFF_SPOS);
    unsigned short* src_s = (unsigned short*)(ws + OFF_SRCS);
    int*   rvt    = (int*)(ws + OFF_RVT);
    int*   rv_s   = (int*)(ws + OFF_RVS);
    unsigned long long* recbuf2 = (unsigned long long*)(ws + OFF_REC2);
    int*   gcur2  = (int*)(ws + OFF_GCUR2);

    const int edgeBlocks  = (kE / 4 + 255) / 256;            // 1563
    const int buildBlocks = (kE / 2 + 255) / 256;            // 3125
    const int nodeBlocks  = ((kN + 1) / 2 * 64 + 255) / 256; // 6250
    const int binBlocks   = (kE + kChunk - 1) / kChunk;      // 391

    (void)hipMemsetAsync(bhist, 0, kNB * sizeof(int), stream);
    init_kernel<<<1280, 256, 0, stream>>>(x, W, bias, log_b0, out, dst, bhist);
    bucket_scan_kernel<<<1, 256, 0, stream>>>(bhist, gbase, gcur, gcur2);
    bin_kernel<<<binBlocks, 256, 0, stream>>>(dst, src, rv, gcur, recbuf, paybuf);
    fine_kernel<<<kNB, 256, 0, stream>>>(gbase, recbuf, paybuf, start, inv, src_s, rvt);
    bin2_kernel<<<binBlocks, 256, 0, stream>>>(inv, gcur2, recbuf2);
    fine2_kernel<<<kNB, 256, 0, stream>>>(recbuf2, spos);
    build_kernel<<<buildBlocks, 256, 0, stream>>>(rvt, spos, rv_s);

    // step 0 (uniform initial msg cancels in softmax)
    edge_kernel<true><<<edgeBlocks, 256, 0, stream>>>(src_s, rv_s, out, msgB, msgA);
    node_kernel<false><<<nodeBlocks, 256, 0, stream>>>(start, msgA, log_b0, out);

    unsigned char* cur = msgA;
    unsigned char* nxt = msgB;
    for (int it = 1; it < kSteps; ++it) {
        edge_kernel<false><<<edgeBlocks, 256, 0, stream>>>(src_s, rv_s, out, cur, nxt);
        if (it == kSteps - 1)
            node_kernel<true><<<nodeBlocks, 256, 0, stream>>>(start, nxt, log_b0, out);
        else
            node_kernel<false><<<nodeBlocks, 256, 0, stream>>>(start, nxt, log_b0, out);
        unsigned char* tmp = cur; cur = nxt; nxt = tmp;
    }
}